// Round 11
// baseline (573.513 us; speedup 1.0000x reference)
//
#include <hip/hip_runtime.h>
#include <hip/hip_fp16.h>
#include <stdint.h>
#include <math.h>

#define N_TOK 4096
#define DIM   512
#define HID   2048
#define NE    8
#define NSLOT (2 * N_TOK)
#define KS    4            // split-K factor for mlp2

#define HALF_LOG_2PI 0.91893853320467274178f

using half8 = __attribute__((ext_vector_type(8))) _Float16;
using f32x4 = __attribute__((ext_vector_type(4))) float;
using u16x8 = __attribute__((ext_vector_type(8))) unsigned short;

__device__ __forceinline__ float gelu_exact(float v) {
  return 0.5f * v * (1.0f + erff(v * 0.70710678118654752440f));
}

// split fp32 into fp16 hi + fp16 lo (residual)
__device__ __forceinline__ void split2u(float x, unsigned short& h, unsigned short& l) {
  __half hh = __float2half(x);
  h = __half_as_ushort(hh);
  l = __half_as_ushort(__float2half(x - __half2float(hh)));
}

// ---------------- router: 1 wave per token ----------------
__global__ __launch_bounds__(256) void router_kernel(
    const float* __restrict__ x, const float* __restrict__ mus,
    const float* __restrict__ ls, float* __restrict__ out_logp,
    float* __restrict__ out_w, float* __restrict__ out_idx,
    float* __restrict__ wts, int* __restrict__ bucket, int* __restrict__ counts)
{
  const int lane = threadIdx.x & 63;
  const int n = blockIdx.x * 4 + (threadIdx.x >> 6);

  const float* xr = x + (size_t)n * DIM;
  const float4 xv0 = *(const float4*)(xr + lane * 4);
  const float4 xv1 = *(const float4*)(xr + 256 + lane * 4);

  float logp[NE];
#pragma unroll
  for (int e = 0; e < NE; ++e) {
    const float* mr = mus + e * DIM;
    const float* lr = ls + e * DIM;
    const float4 m0 = *(const float4*)(mr + lane * 4);
    const float4 m1 = *(const float4*)(mr + 256 + lane * 4);
    const float4 l0 = *(const float4*)(lr + lane * 4);
    const float4 l1 = *(const float4*)(lr + 256 + lane * 4);
    float s = 0.0f, z;
    z = (xv0.x - m0.x) * expf(-l0.x); s += 0.5f*z*z + l0.x;
    z = (xv0.y - m0.y) * expf(-l0.y); s += 0.5f*z*z + l0.y;
    z = (xv0.z - m0.z) * expf(-l0.z); s += 0.5f*z*z + l0.z;
    z = (xv0.w - m0.w) * expf(-l0.w); s += 0.5f*z*z + l0.w;
    z = (xv1.x - m1.x) * expf(-l1.x); s += 0.5f*z*z + l1.x;
    z = (xv1.y - m1.y) * expf(-l1.y); s += 0.5f*z*z + l1.y;
    z = (xv1.z - m1.z) * expf(-l1.z); s += 0.5f*z*z + l1.z;
    z = (xv1.w - m1.w) * expf(-l1.w); s += 0.5f*z*z + l1.w;
#pragma unroll
    for (int off = 32; off > 0; off >>= 1) s += __shfl_xor(s, off);
    logp[e] = -s - DIM * HALF_LOG_2PI;
  }

  // top-2 (ties toward lower index, matching jax.lax.top_k)
  float best = -INFINITY, second = -INFINITY;
  int bi = 0, si = 0;
#pragma unroll
  for (int e = 0; e < NE; ++e) {
    float v = logp[e];
    if (v > best) { second = best; si = bi; best = v; bi = e; }
    else if (v > second) { second = v; si = e; }
  }
  float ew = expf(second - best);
  float w0 = 1.0f / (1.0f + ew);
  float w1 = ew * w0;

#pragma unroll
  for (int e = 0; e < NE; ++e)
    if (lane == e) out_logp[(size_t)n * NE + e] = logp[e];

  if (lane == 0) {
    out_w[n * 2 + 0] = w0;
    out_w[n * 2 + 1] = w1;
    out_idx[n * 2 + 0] = (float)bi;
    out_idx[n * 2 + 1] = (float)si;
    wts[n * 2 + 0] = w0;
    wts[n * 2 + 1] = w1;
    int p0 = atomicAdd(&counts[bi], 1);
    bucket[bi * N_TOK + p0] = n * 2 + 0;
    int p1 = atomicAdd(&counts[si], 1);
    bucket[si * N_TOK + p1] = n * 2 + 1;
  }
}

__global__ void scan_kernel(const int* __restrict__ counts, int* __restrict__ offs) {
  int acc = 0;
  for (int e = 0; e < NE; ++e) { offs[e] = acc; acc += counts[e]; }
}

// ---------------- x pre-split: f32 -> separate hi/lo ushort planes ----------------
__global__ __launch_bounds__(256) void x_split(
    const float* __restrict__ x, unsigned short* __restrict__ xh,
    unsigned short* __restrict__ xl)
{
  const size_t i = ((size_t)blockIdx.x * 256 + threadIdx.x) * 8;
  const float4 v0 = *(const float4*)(x + i);
  const float4 v1 = *(const float4*)(x + i + 4);
  const float vv[8] = {v0.x, v0.y, v0.z, v0.w, v1.x, v1.y, v1.z, v1.w};
  u16x8 h, l;
#pragma unroll
  for (int j = 0; j < 8; ++j) {
    unsigned short hh, ll;
    split2u(vv[j], hh, ll);
    h[j] = hh; l[j] = ll;
  }
  *(u16x8*)(xh + i) = h;
  *(u16x8*)(xl + i) = l;
}

// ---------------- W transpose + split into hi/lo planes ----------------
// W: [e][K][N] f32  ->  Wh/Wl: [e][N][K] ushort
__global__ __launch_bounds__(256) void transpose_split(
    const float* __restrict__ W, unsigned short* __restrict__ Wh,
    unsigned short* __restrict__ Wl, int K, int N)
{
  const int e = blockIdx.z;
  const int k0 = blockIdx.y * 64, n0 = blockIdx.x * 64;
  __shared__ float tile[64][65];
  const int t = threadIdx.x;
  const int r = t >> 2, c0 = t & 3;

  const float* src = W + ((size_t)e * K + k0 + r) * N + n0;
#pragma unroll
  for (int j = 0; j < 4; ++j) {
    const int col = (c0 + j * 4) * 4;
    float4 v = *(const float4*)(src + col);
    tile[r][col + 0] = v.x; tile[r][col + 1] = v.y;
    tile[r][col + 2] = v.z; tile[r][col + 3] = v.w;
  }
  __syncthreads();
  // thread (r, c0) writes dst row n0+r, k-range k0 + c0*16 .. +16
  const size_t dbase = ((size_t)e * N + n0 + r) * K + k0 + c0 * 16;
  u16x8 h0, l0, h1, l1;
#pragma unroll
  for (int m = 0; m < 8; ++m) {
    unsigned short hh, ll;
    split2u(tile[c0 * 16 + m][r], hh, ll);
    h0[m] = hh; l0[m] = ll;
  }
#pragma unroll
  for (int m = 0; m < 8; ++m) {
    unsigned short hh, ll;
    split2u(tile[c0 * 16 + 8 + m][r], hh, ll);
    h1[m] = hh; l1[m] = ll;
  }
  *(u16x8*)(Wh + dbase) = h0;  *(u16x8*)(Wh + dbase + 8) = h1;
  *(u16x8*)(Wl + dbase) = l0;  *(u16x8*)(Wl + dbase + 8) = l1;
}

// ---------------- MFMA grouped GEMM, NO LDS ----------------
// Each wave loads its fragments directly from global (L2-resident operands) as
// dwordx4; separate hi/lo planes mean a 16B load IS a half8 (zero unpack VALU).
// No barriers: waves fully independent; register double-buffer (k+32 ahead).

// pass 1: h2{h,l}[slot,:] = split(gelu(x[tok] @ W1[e] + b1[e]))
__global__ __launch_bounds__(256, 2) void mlp1_mfma(
    const unsigned short* __restrict__ xh, const unsigned short* __restrict__ xl,
    const unsigned short* __restrict__ W1h, const unsigned short* __restrict__ W1l,
    const float* __restrict__ b1, const int* __restrict__ bucket,
    const int* __restrict__ counts, const int* __restrict__ offs,
    unsigned short* __restrict__ h2h, unsigned short* __restrict__ h2l)
{
  const int e = blockIdx.z;
  const int cnt = counts[e];
  const int i0 = blockIdx.y * 128;
  if (i0 >= cnt) return;
  const int n0 = blockIdx.x * 128;
  const int t = threadIdx.x;
  const int lane = t & 63, w = t >> 6;
  const int wr = w >> 1, wc = w & 1;
  const int fl = lane & 15, kg = lane >> 4;

  // loop-invariant per-lane source offsets (ushort units)
  size_t aoff[4], boff[4];
#pragma unroll
  for (int fr = 0; fr < 4; ++fr) {
    const int r = wr * 64 + fr * 16 + fl;
    const int tok = (i0 + r < cnt) ? (bucket[e * N_TOK + i0 + r] >> 1) : 0;
    aoff[fr] = (size_t)tok * DIM + kg * 8;
  }
#pragma unroll
  for (int fc = 0; fc < 4; ++fc)
    boff[fc] = ((size_t)e * HID + n0 + wc * 64 + fc * 16 + fl) * DIM + kg * 8;

  f32x4 acc[4][4] = {};
  half8 a0h[4], a0l[4], b0h[4], b0l[4];
  half8 a1h[4], a1l[4], b1h[4], b1l[4];

#define LD1(AH, AL, BH, BL, KOFF) \
  { _Pragma("unroll") for (int f_ = 0; f_ < 4; ++f_) { \
      AH[f_] = *(const half8*)(xh  + aoff[f_] + (KOFF)); \
      AL[f_] = *(const half8*)(xl  + aoff[f_] + (KOFF)); \
      BH[f_] = *(const half8*)(W1h + boff[f_] + (KOFF)); \
      BL[f_] = *(const half8*)(W1l + boff[f_] + (KOFF)); } }

#define MM(AH, AL, BH, BL) \
  { _Pragma("unroll") for (int fc_ = 0; fc_ < 4; ++fc_) { \
      _Pragma("unroll") for (int fr_ = 0; fr_ < 4; ++fr_) \
        acc[fr_][fc_] = __builtin_amdgcn_mfma_f32_16x16x32_f16(AH[fr_], BH[fc_], acc[fr_][fc_], 0, 0, 0); \
      _Pragma("unroll") for (int fr_ = 0; fr_ < 4; ++fr_) \
        acc[fr_][fc_] = __builtin_amdgcn_mfma_f32_16x16x32_f16(AL[fr_], BH[fc_], acc[fr_][fc_], 0, 0, 0); \
      _Pragma("unroll") for (int fr_ = 0; fr_ < 4; ++fr_) \
        acc[fr_][fc_] = __builtin_amdgcn_mfma_f32_16x16x32_f16(AH[fr_], BL[fc_], acc[fr_][fc_], 0, 0, 0); } }

  LD1(a0h, a0l, b0h, b0l, 0);
  for (int k0 = 0; k0 < DIM; k0 += 64) {
    LD1(a1h, a1l, b1h, b1l, k0 + 32);
    MM(a0h, a0l, b0h, b0l);
    if (k0 + 64 < DIM) LD1(a0h, a0l, b0h, b0l, k0 + 64);
    MM(a1h, a1l, b1h, b1l);
  }
#undef LD1

  // epilogue: bias + gelu + split (C/D map: col=lane&15, row=kg*4+q)
  const int hbase = offs[e] + i0;
  const float* b1e = b1 + (size_t)e * HID;
  float bs[4];
#pragma unroll
  for (int fc = 0; fc < 4; ++fc) bs[fc] = b1e[n0 + wc * 64 + fc * 16 + fl];
#pragma unroll
  for (int fr = 0; fr < 4; ++fr)
#pragma unroll
    for (int q = 0; q < 4; ++q) {
      const int lr = wr * 64 + fr * 16 + kg * 4 + q;
      if (i0 + lr < cnt) {
        const size_t hb = (size_t)(hbase + lr) * HID + n0 + wc * 64 + fl;
#pragma unroll
        for (int fc = 0; fc < 4; ++fc) {
          unsigned short hh, ll;
          split2u(gelu_exact(acc[fr][fc][q] + bs[fc]), hh, ll);
          h2h[hb + fc * 16] = hh;
          h2l[hb + fc * 16] = ll;
        }
      }
    }
}

// pass 2 (split-K x4): y[tok,:] += w * (h[slot] @ W2[e] + b2[e])
__global__ __launch_bounds__(256, 2) void mlp2_mfma(
    const unsigned short* __restrict__ h2h, const unsigned short* __restrict__ h2l,
    const unsigned short* __restrict__ W2h, const unsigned short* __restrict__ W2l,
    const float* __restrict__ b2, const int* __restrict__ bucket,
    const int* __restrict__ counts, const int* __restrict__ offs,
    const float* __restrict__ wts, float* __restrict__ y)
{
  const int e = blockIdx.z;
  const int cnt = counts[e];
  const int i0 = blockIdx.y * 128;
  if (i0 >= cnt) return;
  const int n0 = (blockIdx.x & 3) * 128;   // n-block
  const int kc = blockIdx.x >> 2;          // k-chunk, 0..KS-1
  const int kb = kc * (HID / KS);          // k base
  const int t = threadIdx.x;
  const int lane = t & 63, w = t >> 6;
  const int wr = w >> 1, wc = w & 1;
  const int fl = lane & 15, kg = lane >> 4;

  size_t aoff[4], boff[4];
#pragma unroll
  for (int fr = 0; fr < 4; ++fr) {
    const int r = wr * 64 + fr * 16 + fl;
    const int slot = offs[e] + ((i0 + r < cnt) ? (i0 + r) : 0);
    aoff[fr] = (size_t)slot * HID + kb + kg * 8;
  }
#pragma unroll
  for (int fc = 0; fc < 4; ++fc)
    boff[fc] = ((size_t)e * DIM + n0 + wc * 64 + fc * 16 + fl) * HID + kb + kg * 8;

  f32x4 acc[4][4] = {};
  half8 a0h[4], a0l[4], b0h[4], b0l[4];
  half8 a1h[4], a1l[4], b1h[4], b1l[4];

#define LD2(AH, AL, BH, BL, KOFF) \
  { _Pragma("unroll") for (int f_ = 0; f_ < 4; ++f_) { \
      AH[f_] = *(const half8*)(h2h + aoff[f_] + (KOFF)); \
      AL[f_] = *(const half8*)(h2l + aoff[f_] + (KOFF)); \
      BH[f_] = *(const half8*)(W2h + boff[f_] + (KOFF)); \
      BL[f_] = *(const half8*)(W2l + boff[f_] + (KOFF)); } }

  LD2(a0h, a0l, b0h, b0l, 0);
  for (int k0 = 0; k0 < HID / KS; k0 += 64) {
    LD2(a1h, a1l, b1h, b1l, k0 + 32);
    MM(a0h, a0l, b0h, b0l);
    if (k0 + 64 < HID / KS) LD2(a0h, a0l, b0h, b0l, k0 + 64);
    MM(a1h, a1l, b1h, b1l);
  }
#undef LD2
#undef MM

  // bias added exactly once (kc==0 block)
  const float* b2e = b2 + (size_t)e * DIM;
  float bs[4];
#pragma unroll
  for (int fc = 0; fc < 4; ++fc)
    bs[fc] = (kc == 0) ? b2e[n0 + wc * 64 + fc * 16 + fl] : 0.0f;
#pragma unroll
  for (int fr = 0; fr < 4; ++fr)
#pragma unroll
    for (int q = 0; q < 4; ++q) {
      const int lr = wr * 64 + fr * 16 + kg * 4 + q;
      if (i0 + lr < cnt) {
        const int ent = bucket[e * N_TOK + i0 + lr];
        const int tk = ent >> 1;
        const float wgt = wts[ent];
        float* yr = y + (size_t)tk * DIM + n0 + wc * 64 + fl;
#pragma unroll
        for (int fc = 0; fc < 4; ++fc)
          atomicAdd(yr + fc * 16, wgt * (acc[fr][fc][q] + bs[fc]));
      }
    }
}

extern "C" void kernel_launch(void* const* d_in, const int* in_sizes, int n_in,
                              void* d_out, int out_size, void* d_ws, size_t ws_size,
                              hipStream_t stream) {
  const float* x   = (const float*)d_in[0];
  const float* mus = (const float*)d_in[1];
  const float* ls  = (const float*)d_in[2];
  const float* W1  = (const float*)d_in[3];
  const float* b1  = (const float*)d_in[4];
  const float* W2  = (const float*)d_in[5];
  const float* b2  = (const float*)d_in[6];

  float* out      = (float*)d_out;
  float* y        = out;                           // [N_TOK, DIM]
  float* out_logp = out + (size_t)N_TOK * DIM;     // [N_TOK, NE]
  float* out_w    = out_logp + (size_t)N_TOK * NE; // [N_TOK, 2]
  float* out_idx  = out_w + (size_t)N_TOK * 2;     // [N_TOK, 2] (as float)

  // workspace layout (ushort planes; every array length is a multiple of 8
  // elements so 16B alignment is preserved)
  unsigned short* W1h = (unsigned short*)d_ws;            // [NE][HID][DIM]
  unsigned short* W1l = W1h + (size_t)NE * HID * DIM;
  unsigned short* W2h = W1l + (size_t)NE * HID * DIM;     // [NE][DIM][HID]
  unsigned short* W2l = W2h + (size_t)NE * DIM * HID;
  unsigned short* h2h = W2l + (size_t)NE * DIM * HID;     // [NSLOT][HID]
  unsigned short* h2l = h2h + (size_t)NSLOT * HID;
  unsigned short* xh  = h2l + (size_t)NSLOT * HID;        // [N_TOK][DIM]
  unsigned short* xl  = xh + (size_t)N_TOK * DIM;
  int* bucket   = (int*)(xl + (size_t)N_TOK * DIM);       // [NE][N_TOK]
  float* wts    = (float*)(bucket + NE * N_TOK);          // [N_TOK][2]
  int* counts   = (int*)(wts + 2 * N_TOK);                // [NE]
  int* offs     = counts + NE;                            // [NE]

  hipMemsetAsync(y, 0, (size_t)N_TOK * DIM * sizeof(float), stream);
  hipMemsetAsync(counts, 0, NE * sizeof(int), stream);

  router_kernel<<<N_TOK / 4, 256, 0, stream>>>(x, mus, ls, out_logp, out_w,
                                               out_idx, wts, bucket, counts);
  scan_kernel<<<1, 1, 0, stream>>>(counts, offs);

  x_split<<<(N_TOK * DIM / 8) / 256, 256, 0, stream>>>(x, xh, xl);
  transpose_split<<<dim3(HID / 64, DIM / 64, NE), 256, 0, stream>>>(W1, W1h, W1l, DIM, HID);
  transpose_split<<<dim3(DIM / 64, HID / 64, NE), 256, 0, stream>>>(W2, W2h, W2l, HID, DIM);

  mlp1_mfma<<<dim3(HID / 128, N_TOK / 128, NE), 256, 0, stream>>>(
      xh, xl, W1h, W1l, b1, bucket, counts, offs, h2h, h2l);
  mlp2_mfma<<<dim3((DIM / 128) * KS, N_TOK / 128, NE), 256, 0, stream>>>(
      h2h, h2l, W2h, W2l, b2, bucket, counts, offs, wts, y);
}